// Round 1
// baseline (176.821 us; speedup 1.0000x reference)
//
#include <hip/hip_runtime.h>
#include <hip/hip_bf16.h>

// Problem constants (from reference)
#define NN 20000
#define EE 320000
#define KK 4
#define FIN 512
#define FHID 256
#define FOUT 128
#define FHD 256
#define NH (2*FOUT+3)   // 259
#define CAP1 1024       // max edges into the 2 target nodes (expected ~32)
#define MS (CAP1+2)     // slots: [t0, t1, L1 sources...]
#define CAP2 16384      // max layer-1 edges into slot nodes (expected ~650)

__device__ __forceinline__ float dinvf(int indeg) {
  // degree includes the self-loop -> always >= 1
  return rsqrtf((float)(indeg + 1));
}

// Pass 1: full edge scan -> in-degrees (int atomics, exact) + collect edges whose dst is a target
__global__ __launch_bounds__(256) void scan1(const int* __restrict__ ei,
                                             const int* __restrict__ idx,
                                             int* __restrict__ deg,
                                             int* __restrict__ cnt1,
                                             int* __restrict__ L1src,
                                             int* __restrict__ L1sel) {
  int k = blockIdx.y;
  int e = blockIdx.x * blockDim.x + threadIdx.x;
  if (e >= EE) return;
  const int* srcp = ei + (size_t)k * 2 * EE;
  const int* dstp = srcp + EE;
  int d = dstp[e];
  atomicAdd(&deg[k * NN + d], 1);
  int t0 = idx[k * 2], t1 = idx[k * 2 + 1];
  if (d == t0) {
    int p = atomicAdd(&cnt1[k], 1);
    if (p < CAP1) { L1src[k * CAP1 + p] = srcp[e]; L1sel[k * CAP1 + p] = 0; }
  }
  if (d == t1) {
    int p = atomicAdd(&cnt1[k], 1);
    if (p < CAP1) { L1src[k * CAP1 + p] = srcp[e]; L1sel[k * CAP1 + p] = 1; }
  }
}

// Append the layer-1 self-loop entries (u == slot node, norm = dinv^2)
__global__ __launch_bounds__(256) void selfappend(const int* __restrict__ idx,
                                                  const int* __restrict__ deg,
                                                  const int* __restrict__ cnt1,
                                                  const int* __restrict__ L1src,
                                                  int* __restrict__ cnt2,
                                                  int* __restrict__ L2u,
                                                  int* __restrict__ L2slot,
                                                  float* __restrict__ L2norm) {
  int k = blockIdx.y;
  int i = blockIdx.x * blockDim.x + threadIdx.x;
  int m = min(cnt1[k], CAP1) + 2;
  if (i >= m) return;
  int node = (i == 0) ? idx[k * 2] : (i == 1) ? idx[k * 2 + 1] : L1src[k * CAP1 + i - 2];
  float di = dinvf(deg[k * NN + node]);
  int p = atomicAdd(&cnt2[k], 1);
  if (p < CAP2) { L2u[k * CAP2 + p] = node; L2slot[k * CAP2 + p] = i; L2norm[k * CAP2 + p] = di * di; }
}

// Pass 2: full edge scan -> edges whose dst is any slot node (per-slot, duplicates intended)
__global__ __launch_bounds__(256) void scan2(const int* __restrict__ ei,
                                             const int* __restrict__ idx,
                                             const int* __restrict__ deg,
                                             const int* __restrict__ cnt1,
                                             const int* __restrict__ L1src,
                                             int* __restrict__ cnt2,
                                             int* __restrict__ L2u,
                                             int* __restrict__ L2slot,
                                             float* __restrict__ L2norm) {
  __shared__ int Snode[MS];
  __shared__ float Sdinv[MS];
  int k = blockIdx.y;
  int m = min(cnt1[k], CAP1) + 2;
  for (int i = threadIdx.x; i < m; i += blockDim.x) {
    int node = (i == 0) ? idx[k * 2] : (i == 1) ? idx[k * 2 + 1] : L1src[k * CAP1 + i - 2];
    Snode[i] = node;
    Sdinv[i] = dinvf(deg[k * NN + node]);
  }
  __syncthreads();
  int e = blockIdx.x * blockDim.x + threadIdx.x;
  if (e >= EE) return;
  const int* srcp = ei + (size_t)k * 2 * EE;
  int s = srcp[e];
  int d = srcp[EE + e];
  float dis = -1.f;
  for (int i = 0; i < m; i++) {
    if (Snode[i] == d) {
      if (dis < 0.f) dis = dinvf(deg[k * NN + s]);
      float nrm = dis * Sdinv[i];
      int p = atomicAdd(&cnt2[k], 1);
      if (p < CAP2) { L2u[k * CAP2 + p] = s; L2slot[k * CAP2 + p] = i; L2norm[k * CAP2 + p] = nrm; }
    }
  }
}

// Phase 3: for each L2 entry (u, slot, norm): h1[slot] += norm * (x[u] @ W1)
__global__ __launch_bounds__(256) void phase3(const int* __restrict__ L2u,
                                              const int* __restrict__ L2slot,
                                              const float* __restrict__ L2norm,
                                              const int* __restrict__ cnt2,
                                              const float* __restrict__ x,
                                              const float* __restrict__ W1,
                                              float* __restrict__ h1) {
  __shared__ float xrow[FIN];
  int k = blockIdx.y;
  int n2 = min(cnt2[k], CAP2);
  for (int it = blockIdx.x; it < n2; it += gridDim.x) {
    int u = L2u[k * CAP2 + it];
    int slot = L2slot[k * CAP2 + it];
    float nrm = L2norm[k * CAP2 + it];
    __syncthreads();
    for (int i = threadIdx.x; i < FIN; i += blockDim.x) xrow[i] = x[(size_t)u * FIN + i];
    __syncthreads();
    int j = threadIdx.x;  // FHID == 256 == blockDim.x
    float acc = 0.f;
    #pragma unroll 8
    for (int kk = 0; kk < FIN; kk++) acc += xrow[kk] * W1[kk * FHID + j];
    atomicAdd(&h1[((size_t)k * MS + slot) * FHID + j], acc * nrm);
  }
}

// Phase 4: HW2[slot] = relu(h1[slot] + b1) @ W2
__global__ __launch_bounds__(128) void phase4(const float* __restrict__ h1,
                                              const float* __restrict__ b1,
                                              const float* __restrict__ W2,
                                              const int* __restrict__ cnt1,
                                              float* __restrict__ HW2) {
  __shared__ float hrow[FHID];
  int k = blockIdx.y;
  int m = min(cnt1[k], CAP1) + 2;
  for (int s = blockIdx.x; s < m; s += gridDim.x) {
    __syncthreads();
    for (int i = threadIdx.x; i < FHID; i += blockDim.x) {
      float v = h1[((size_t)k * MS + s) * FHID + i] + b1[i];
      hrow[i] = v > 0.f ? v : 0.f;
    }
    __syncthreads();
    int j = threadIdx.x;  // FOUT == 128 == blockDim.x
    float acc = 0.f;
    #pragma unroll 8
    for (int kk = 0; kk < FHID; kk++) acc += hrow[kk] * W2[kk * FOUT + j];
    HW2[((size_t)k * MS + s) * FOUT + j] = acc;
  }
}

// Phase 5+6 fused: mu rows for t0,t1 (+b2), then decoder MLP -> sigmoid -> out[k]
__global__ __launch_bounds__(256) void phase56(const float* __restrict__ HW2,
                                               const float* __restrict__ b2,
                                               const int* __restrict__ cnt1,
                                               const int* __restrict__ L1src,
                                               const int* __restrict__ L1sel,
                                               const int* __restrict__ idx,
                                               const int* __restrict__ deg,
                                               const float* __restrict__ value,
                                               const float* __restrict__ Wd,
                                               const float* __restrict__ bd,
                                               const float* __restrict__ Wp,
                                               const float* __restrict__ bp,
                                               float* __restrict__ out) {
  __shared__ float h[NH + 1];
  __shared__ float o[FHD];
  __shared__ float red[4];
  int k = blockIdx.x;
  int tid = threadIdx.x;
  int n1 = min(cnt1[k], CAP1);
  int tsel = tid >> 7, j = tid & 127;
  int t = idx[k * 2 + tsel];
  float dit = dinvf(deg[k * NN + t]);
  // self-loop term + b2
  float acc = b2[j] + dit * dit * HW2[((size_t)k * MS + tsel) * FOUT + j];
  for (int i = 0; i < n1; i++) {
    if (L1sel[k * CAP1 + i] == tsel) {
      int s = L1src[k * CAP1 + i];
      float dis = dinvf(deg[k * NN + s]);
      acc += dis * dit * HW2[((size_t)k * MS + 2 + i) * FOUT + j];
    }
  }
  h[tsel * FOUT + j] = acc;
  if (tid < 3) h[2 * FOUT + tid] = value[k * 3 + tid];
  __syncthreads();
  // decoder layer 1: o = relu(h @ Wd + bd), FHD == 256 == blockDim.x
  float a2 = bd[tid];
  for (int i = 0; i < NH; i++) a2 += h[i] * Wd[i * FHD + tid];
  o[tid] = a2 > 0.f ? a2 : 0.f;
  __syncthreads();
  // decoder layer 2: p = sigmoid(o @ Wp + bp)
  float r = o[tid] * Wp[tid];
  for (int off = 32; off > 0; off >>= 1) r += __shfl_down(r, off);
  if ((tid & 63) == 0) red[tid >> 6] = r;
  __syncthreads();
  if (tid == 0) {
    float ssum = red[0] + red[1] + red[2] + red[3] + bp[0];
    out[k] = 1.f / (1.f + expf(-ssum));
  }
}

extern "C" void kernel_launch(void* const* d_in, const int* in_sizes, int n_in,
                              void* d_out, int out_size, void* d_ws, size_t ws_size,
                              hipStream_t stream) {
  const float* x     = (const float*)d_in[0];
  const int*   ei    = (const int*)d_in[1];
  const float* value = (const float*)d_in[2];
  const int*   idx   = (const int*)d_in[3];
  const float* W1    = (const float*)d_in[4];
  const float* b1    = (const float*)d_in[5];
  const float* W2    = (const float*)d_in[6];
  const float* b2    = (const float*)d_in[7];
  const float* Wd    = (const float*)d_in[8];
  const float* bd    = (const float*)d_in[9];
  const float* Wp    = (const float*)d_in[10];
  const float* bp    = (const float*)d_in[11];
  float* out = (float*)d_out;

  // Workspace carve-up
  char* ws = (char*)d_ws;
  size_t off = 0;
  auto alloc = [&](size_t bytes) -> void* {
    void* p = ws + off;
    off = (off + bytes + 255) & ~(size_t)255;
    return p;
  };
  // deg + cnt1 + cnt2 contiguous so one memset covers them
  int* deg = (int*)alloc((size_t)(KK * NN + 2 * KK) * sizeof(int));
  int* cnt1 = deg + KK * NN;
  int* cnt2 = cnt1 + KK;
  int* L1src = (int*)alloc((size_t)KK * CAP1 * sizeof(int));
  int* L1sel = (int*)alloc((size_t)KK * CAP1 * sizeof(int));
  int* L2u = (int*)alloc((size_t)KK * CAP2 * sizeof(int));
  int* L2slot = (int*)alloc((size_t)KK * CAP2 * sizeof(int));
  float* L2norm = (float*)alloc((size_t)KK * CAP2 * sizeof(float));
  float* h1 = (float*)alloc((size_t)KK * MS * FHID * sizeof(float));
  float* HW2 = (float*)alloc((size_t)KK * MS * FOUT * sizeof(float));
  (void)ws_size; (void)in_sizes; (void)n_in; (void)out_size;

  hipMemsetAsync(deg, 0, (size_t)(KK * NN + 2 * KK) * sizeof(int), stream);
  hipMemsetAsync(h1, 0, (size_t)KK * MS * FHID * sizeof(float), stream);

  dim3 escan((EE + 255) / 256, KK);
  scan1<<<escan, 256, 0, stream>>>(ei, idx, deg, cnt1, L1src, L1sel);
  selfappend<<<dim3((MS + 255) / 256, KK), 256, 0, stream>>>(idx, deg, cnt1, L1src,
                                                             cnt2, L2u, L2slot, L2norm);
  scan2<<<escan, 256, 0, stream>>>(ei, idx, deg, cnt1, L1src, cnt2, L2u, L2slot, L2norm);
  phase3<<<dim3(1024, KK), 256, 0, stream>>>(L2u, L2slot, L2norm, cnt2, x, W1, h1);
  phase4<<<dim3(64, KK), 128, 0, stream>>>(h1, b1, W2, cnt1, HW2);
  phase56<<<dim3(KK), 256, 0, stream>>>(HW2, b2, cnt1, L1src, L1sel, idx, deg, value,
                                        Wd, bd, Wp, bp, out);
}